// Round 6
// baseline (290.804 us; speedup 1.0000x reference)
//
#include <hip/hip_runtime.h>

#define NC 91
#define NBIN 182          // g_hist: [b][0..90]=union, [b][91..181]=inter
#define NB 32
#define HW (1024 * 1024)
#define NT 256
#define PPT 128
#define PIX_PER_BLOCK (NT * PPT)   // 32768 -> 32 blocks per image, 1024 total = 4/CU
#define JS 96             // padded joint-histogram dim/stride

__global__ __launch_bounds__(256) void hist_kernel(const int* __restrict__ x,
                                                   const int* __restrict__ t,
                                                   int* __restrict__ g_hist) {
    // ONE shared joint histogram per block: J[x][t]. One ds_add per pixel.
    __shared__ unsigned int J[JS * JS];         // 36,864 B
    __shared__ unsigned int colpart[4][JS];     // per-wave column partials
    __shared__ unsigned int rowsum[JS], colsum[JS];

    const int tid = threadIdx.x;
    for (int i = tid; i < JS * JS; i += NT) J[i] = 0u;
    __syncthreads();

    const int b = blockIdx.y;
    const long base = (long)b * HW + (long)blockIdx.x * PIX_PER_BLOCK;
    const int4* __restrict__ x4 = (const int4*)(x + base) + tid;
    const int4* __restrict__ t4 = (const int4*)(t + base) + tid;

#pragma unroll 4
    for (int i = 0; i < PPT / 4; ++i) {
        int4 xv = x4[i * NT];
        int4 tv = t4[i * NT];
        // single update per pixel: joint histogram (no-return ds_add_u32)
        atomicAdd(&J[xv.x * JS + tv.x], 1u);
        atomicAdd(&J[xv.y * JS + tv.y], 1u);
        atomicAdd(&J[xv.z * JS + tv.z], 1u);
        atomicAdd(&J[xv.w * JS + tv.w], 1u);
    }
    __syncthreads();

    const int wave = tid >> 6, lane = tid & 63;

    // column sums (cnt_t): per-lane column accumulators, row-major coalesced reads.
    {
        unsigned ca = 0, cb = 0;
        const int m0 = wave * (JS / 4), m1 = m0 + (JS / 4);
        for (int m = m0; m < m1; ++m) {
            ca += J[m * JS + lane];
            if (lane < JS - 64) cb += J[m * JS + 64 + lane];
        }
        colpart[wave][lane] = ca;
        if (lane < JS - 64) colpart[wave][64 + lane] = cb;
    }

    // row sums (cnt_x): coalesced row read + wave shuffle-reduce.
    for (int m = wave; m < JS; m += 4) {
        unsigned r = J[m * JS + lane] + ((lane < JS - 64) ? J[m * JS + 64 + lane] : 0u);
#pragma unroll
        for (int off = 32; off > 0; off >>= 1) r += __shfl_down(r, off, 64);
        if (lane == 0) rowsum[m] = r;
    }
    __syncthreads();

    if (tid < JS)
        colsum[tid] = colpart[0][tid] + colpart[1][tid] + colpart[2][tid] + colpart[3][tid];
    __syncthreads();

    if (tid < NC) {
        unsigned diag = J[tid * JS + tid];
        unsigned un = rowsum[tid] + colsum[tid] - diag;  // cnt_x + cnt_t - inter
        atomicAdd(&g_hist[b * NBIN + tid], (int)un);
        atomicAdd(&g_hist[b * NBIN + NC + tid], (int)diag);
    }
}

__global__ __launch_bounds__(64) void finalize_kernel(const int* __restrict__ g_hist,
                                                      const float* __restrict__ smooth,
                                                      float* __restrict__ out) {
    const int b = blockIdx.x;
    const int lane = threadIdx.x;  // 0..63
    const float s = smooth[0];
    float acc = 0.0f;
    for (int c = lane; c < NC; c += 64) {
        float un = (float)g_hist[b * NBIN + c];
        float in = (float)g_hist[b * NBIN + NC + c];
        acc += (in + s) / (un + s);
    }
#pragma unroll
    for (int off = 32; off > 0; off >>= 1)
        acc += __shfl_down(acc, off, 64);
    if (lane == 0) out[b] = acc / (float)NC;
}

extern "C" void kernel_launch(void* const* d_in, const int* in_sizes, int n_in,
                              void* d_out, int out_size, void* d_ws, size_t ws_size,
                              hipStream_t stream) {
    const int* x = (const int*)d_in[0];
    const int* t = (const int*)d_in[1];
    const float* smooth = (const float*)d_in[2];
    float* out = (float*)d_out;

    int* g_hist = (int*)d_ws;

    hipMemsetAsync(d_ws, 0, NB * NBIN * sizeof(int), stream);

    dim3 grid(HW / PIX_PER_BLOCK, NB);  // 32 x 32 = 1024 blocks = 4/CU
    hist_kernel<<<grid, NT, 0, stream>>>(x, t, g_hist);
    finalize_kernel<<<NB, 64, 0, stream>>>(g_hist, smooth, out);
}